// Round 12
// baseline (405.698 us; speedup 1.0000x reference)
//
#include <hip/hip_runtime.h>
#include <cstdint>

#define HW 16384
#define HH 128
#define WW 128
#define C2 512
#define CQK 32
#define NB_TOT 4

typedef unsigned short u16;
typedef unsigned int u32;

using bf16x8 = __attribute__((ext_vector_type(8))) short;
using f32x4  = __attribute__((ext_vector_type(4))) float;

__device__ __forceinline__ float us2f(u16 u) { return __uint_as_float(((u32)u) << 16); }
__device__ __forceinline__ u16 f2us(float f) {
    u32 u = __float_as_uint(f);
    u = u + 0x7fffu + ((u >> 16) & 1u);
    return (u16)(u >> 16);
}
__device__ __forceinline__ u32 pack2(float a, float b) {
    return (u32)f2us(a) | ((u32)f2us(b) << 16);
}
__device__ __forceinline__ void unpack8(uint4 p, float* f) {
    u32 a[4] = {p.x, p.y, p.z, p.w};
#pragma unroll
    for (int q = 0; q < 4; ++q) {
        f[q * 2 + 0] = __uint_as_float(a[q] << 16);
        f[q * 2 + 1] = __uint_as_float(a[q] & 0xffff0000u);
    }
}
union U8 { uint4 v; u16 s[8]; };

__device__ __forceinline__ void gl_lds16(const void* g, const void* lds) {
    __builtin_amdgcn_global_load_lds(
        (const __attribute__((address_space(1))) unsigned int*)g,
        (__attribute__((address_space(3))) unsigned int*)lds, 16, 0, 0);
}

// ---------------------------------------------------------------------------
// Convert weights fp32 -> bf16. rows [0,64)=q|k, [64,576)=v, [576,1088)=m.
// ---------------------------------------------------------------------------
__global__ __launch_bounds__(256) void convert_weights(
    const float* __restrict__ Wq, const float* __restrict__ Wk,
    const float* __restrict__ Wv, const float* __restrict__ Wm,
    u16* __restrict__ Wall, const float* __restrict__ gamma)
{
    int id = blockIdx.x * 256 + threadIdx.x;  // one float4 each
    if (id >= 1088 * 128) return;
    int row = id >> 7, q4 = id & 127;
    if (row < 576 && gamma[0] == 0.f) return;  // attention-only rows
    const float* src;
    if (row < 32) src = Wq + (size_t)row * 512;
    else if (row < 64) src = Wk + (size_t)(row - 32) * 512;
    else if (row < 576) src = Wv + (size_t)(row - 64) * 512;
    else src = Wm + (size_t)(row - 576) * 512;
    float4 v = *reinterpret_cast<const float4*>(src + q4 * 4);
    alignas(8) u16 h[4] = {f2us(v.x), f2us(v.y), f2us(v.z), f2us(v.w)};
    *reinterpret_cast<uint2*>(Wall + (size_t)row * 512 + q4 * 4) =
        *reinterpret_cast<uint2*>(h);
}

// ---------------------------------------------------------------------------
// FINAL CONV (always runs): out[s,bg,cc,p] = Wm[m]·src + bm.
// src = bf16(x) (gamma==0) or y (gamma!=0), [c][p] layout; transpose in LDS.
// R12: champion structure (BM=512, BN=128, 8 waves, As dbuf, X reg-staged
// 1 ahead) with BK 64->32: LDS 149.5KB -> 74KB -> 2 blocks/CU so the
// co-resident block's VMEM bursts fill this block's compute/drain phases.
// Grid 512 blocks = exactly 2/CU, all co-resident, no tail.
// ---------------------------------------------------------------------------
__global__ __launch_bounds__(512, 4) void conv_final(
    const u16* __restrict__ Wmb, const float* __restrict__ bm,
    const float* __restrict__ x1, const float* __restrict__ x2,
    const u16* __restrict__ y, float* __restrict__ out,
    int b0, const float* __restrict__ gamma)
{
    __shared__ u16 As[2][512 * 32];  // 2x32KB [m][32k], chunk ck at slot ck^(m&3)
    __shared__ u32 Ps[128 * 20];     // 10KB [p][16 dword cols + 4 pad]; dword=(c,c+1)
    const int t = threadIdx.x, lane = t & 63, wid = t >> 6;  // 8 waves
    const int bz = blockIdx.z, bg = b0 + bz;
    const int p0 = blockIdx.x * 128;
    const int l15 = lane & 15, l16 = lane >> 4;
    const bool useY = (gamma[0] != 0.f);
    const int pcol = t & 31, cpair = t >> 5;  // cpair 0..15 (32 ch = 16 pairs)
    const u16* yb = y + (size_t)bz * C2 * HW;

    f32x4 acc[4][8];
#pragma unroll
    for (int i = 0; i < 4; ++i)
#pragma unroll
        for (int j = 0; j < 8; ++j) acc[i][j] = (f32x4)0.f;

    u32 xr[8];  // row ce -> xr[0..3], row ce+1 -> xr[4..7] (pixels pcol+32i)

    auto loadX = [&](int k0) {
        const int ce = k0 + cpair * 2;         // even channel; ce+1 adjacent
        if (useY) {
            const u16* s0 = yb + (size_t)ce * HW + p0;
            const u16* s1 = s0 + HW;
#pragma unroll
            for (int i = 0; i < 4; ++i) {
                int p = pcol + i * 32;
                xr[i] = s0[p]; xr[4 + i] = s1[p];
            }
        } else {
            // ce even -> ce, ce+1 always in the same tensor
            const float* s0 = (ce < 256) ? x1 + ((size_t)bg * 256 + ce) * HW + p0
                                         : x2 + ((size_t)bg * 256 + ce - 256) * HW + p0;
            const float* s1 = s0 + HW;
#pragma unroll
            for (int i = 0; i < 4; ++i) {
                int p = pcol + i * 32;
                xr[i] = __float_as_uint(s0[p]);
                xr[4 + i] = __float_as_uint(s1[p]);
            }
        }
    };
    auto writeX = [&]() {
#pragma unroll
        for (int i = 0; i < 4; ++i) {
            int p = pcol + i * 32;
            u32 d = useY ? (xr[i] | (xr[4 + i] << 16))
                         : pack2(__uint_as_float(xr[i]), __uint_as_float(xr[4 + i]));
            Ps[p * 20 + cpair] = d;
        }
    };
    auto stageW = [&](int k0, int b) {
        // 512 rows x 32ch = 2048 16B-chunks; 4 per thread; XOR swizzle low2
#pragma unroll
        for (int it = 0; it < 4; ++it) {
            int sflat = it * 512 + t;          // LDS 16B-slot index (linear)
            int m = sflat >> 2, slot = sflat & 3;
            int ck = slot ^ (m & 3);           // logical chunk at this slot
            gl_lds16(Wmb + (size_t)m * 512 + k0 + ck * 8, &As[b][sflat * 8]);
        }
    };

    // prologue: fill W buf0 + X
    stageW(0, 0);
    loadX(0);
    writeX();          // auto-waits X loads via reg deps
    __syncthreads();   // drains W gl_lds (vmcnt0) + lgkm

    for (int k = 0; k < 16; ++k) {
        const int cb = k & 1;
        if (k < 15) {
            stageW((k + 1) * 32, cb ^ 1);  // async into other buffer
            loadX((k + 1) * 32);           // regs in flight under compute
        }
        // pin: prefetch VMEM issues BEFORE the MFMA cluster
        __builtin_amdgcn_sched_barrier(0);
        __builtin_amdgcn_s_setprio(1);
        // ---- compute step k: 32 MFMA per wave ----
        {
            bf16x8 af[4];
#pragma unroll
            for (int mi = 0; mi < 4; ++mi) {
                int row = wid * 64 + mi * 16 + l15;
                int slot = l16 ^ (row & 3);
                af[mi] = *(const bf16x8*)&As[cb][row * 32 + slot * 8];
            }
#pragma unroll
            for (int ni = 0; ni < 8; ++ni) {
                bf16x8 bq = *(const bf16x8*)((const u16*)&Ps[(ni * 16 + l15) * 20 + l16 * 4]);
#pragma unroll
                for (int mi = 0; mi < 4; ++mi)
                    acc[mi][ni] = __builtin_amdgcn_mfma_f32_16x16x32_bf16(
                        af[mi], bq, acc[mi][ni], 0, 0, 0);
            }
        }
        __builtin_amdgcn_s_setprio(0);
        __syncthreads();             // all reads of Ps/As[cb] done; W(k+1) landed
        if (k < 15) {
            writeX();                // stage X(k+1) into Ps
            __syncthreads();         // lgkm drain so next compute sees it
        }
    }
    // ---- epilogue: bias + permuted fp32 store ----
#pragma unroll
    for (int mi = 0; mi < 4; ++mi)
#pragma unroll
        for (int ni = 0; ni < 8; ++ni) {
            const int p = p0 + ni * 16 + l15;
#pragma unroll
            for (int r = 0; r < 4; ++r) {
                const int m = wid * 64 + mi * 16 + l16 * 4 + r;
                out[(((size_t)(m >> 8) * NB_TOT + bg) * 256 + (m & 255)) * HW + p] =
                    acc[mi][ni][r] + bm[m];
            }
        }
}

// ---------------------------------------------------------------------------
// xT[bz][p][c] = bf16(x[bg][c][p])  — ATTENTION PATH ONLY (gamma!=0).
// ---------------------------------------------------------------------------
__global__ __launch_bounds__(256) void transpose_x(
    const float* __restrict__ x1, const float* __restrict__ x2,
    u16* __restrict__ xT, int b0, const float* __restrict__ gamma)
{
    if (gamma[0] == 0.f) return;
    __shared__ u16 tile[32][33];
    const int bz = blockIdx.z, bg = b0 + bz;
    const int p0 = blockIdx.x * 32;
    const int tx = threadIdx.x, ty = threadIdx.y;
    for (int cy = 0; cy < 16; ++cy) {
        const int c0 = cy * 32;
#pragma unroll
        for (int u = 0; u < 4; ++u) {
            int c = c0 + ty + u * 8;
            const float* xs = (c < 256) ? x1 + ((size_t)bg * 256 + c) * HW
                                        : x2 + ((size_t)bg * 256 + (c - 256)) * HW;
            tile[ty + u * 8][tx] = f2us(xs[p0 + tx]);
        }
        __syncthreads();
#pragma unroll
        for (int u = 0; u < 4; ++u) {
            int p = p0 + ty + u * 8;
            xT[((size_t)bz * HW + p) * 512 + c0 + tx] = tile[tx][ty + u * 8];
        }
        __syncthreads();
    }
}

// ---------------------------------------------------------------------------
// MFMA 1x1-conv (attention path): out[m][p] = sum_c W[m][c]*xT[p][c].
// MODE 0: M=64 q|k fp32. MODE 1: M=512 -> bf16 v. Both gamma-guarded.
// ---------------------------------------------------------------------------
template <int BM, int MODE>
__global__ __launch_bounds__(256) void conv_mfma(
    const u16* __restrict__ Wb, const float* __restrict__ bias0,
    const float* __restrict__ bias1, const u16* __restrict__ xT,
    float* __restrict__ oQ, float* __restrict__ oK,
    u16* __restrict__ oV, int b0, const float* __restrict__ gamma)
{
    if (gamma[0] == 0.f) return;
    constexpr int FM = BM / 32;
    __shared__ u16 As[BM * 64];
    __shared__ u16 Ps[128 * 64];
    const int t = threadIdx.x, lane = t & 63, wid = t >> 6;
    const int wr = wid >> 1, wc = wid & 1;
    const int bz = blockIdx.z;
    const int p0 = blockIdx.x * 128, m0 = blockIdx.y * BM;
    const u16* xTb = xT + (size_t)bz * HW * 512;
    const int l15 = lane & 15, l16 = lane >> 4;

    f32x4 acc[FM][4];
#pragma unroll
    for (int i = 0; i < FM; ++i)
#pragma unroll
        for (int j = 0; j < 4; ++j) acc[i][j] = (f32x4)0.f;

    for (int c0 = 0; c0 < 512; c0 += 64) {
#pragma unroll
        for (int it = 0; it < BM / 32; ++it) {
            int flat = it * 256 + t;
            int row = flat >> 3, part = flat & 7;
            gl_lds16(Wb + (size_t)(m0 + row) * 512 + c0 + part * 8,
                     As + (it * 256 + wid * 64) * 8);
        }
#pragma unroll
        for (int it = 0; it < 4; ++it) {
            int flat = it * 256 + t;
            int row = flat >> 3, part = flat & 7;
            gl_lds16(xTb + (size_t)(p0 + row) * 512 + c0 + part * 8,
                     Ps + (it * 256 + wid * 64) * 8);
        }
        __syncthreads();
#pragma unroll
        for (int kk = 0; kk < 2; ++kk) {
            bf16x8 af[FM], bfr[4];
#pragma unroll
            for (int mi = 0; mi < FM; ++mi)
                af[mi] = *(const bf16x8*)&As[(wr * (BM / 2) + mi * 16 + l15) * 64 + kk * 32 + l16 * 8];
#pragma unroll
            for (int ni = 0; ni < 4; ++ni)
                bfr[ni] = *(const bf16x8*)&Ps[(wc * 64 + ni * 16 + l15) * 64 + kk * 32 + l16 * 8];
#pragma unroll
            for (int mi = 0; mi < FM; ++mi)
#pragma unroll
                for (int ni = 0; ni < 4; ++ni)
                    acc[mi][ni] = __builtin_amdgcn_mfma_f32_16x16x32_bf16(
                        af[mi], bfr[ni], acc[mi][ni], 0, 0, 0);
        }
        __syncthreads();
    }
#pragma unroll
    for (int mi = 0; mi < FM; ++mi)
#pragma unroll
        for (int ni = 0; ni < 4; ++ni) {
            const int p = p0 + wc * 64 + ni * 16 + l15;
#pragma unroll
            for (int r = 0; r < 4; ++r) {
                const int m = m0 + wr * (BM / 2) + mi * 16 + l16 * 4 + r;
                float val = acc[mi][ni][r];
                if (MODE == 0) {
                    if (m < 32) {
                        val += bias0[m];
                        oQ[((size_t)bz * 32 + m) * HW + p] = val;
                    } else {
                        val += bias1[m - 32];
                        oK[((size_t)bz * 32 + (m - 32)) * HW + p] = val;
                    }
                } else {
                    val += bias0[m];
                    oV[((size_t)bz * 512 + m) * HW + p] = f2us(val);
                }
            }
        }
}

// ---------------------------------------------------------------------------
// 128x128 plane transpose, bf16 (v -> vT). Guarded; plane-looped grid.
// ---------------------------------------------------------------------------
__global__ __launch_bounds__(256) void transpose_bf16(
    const u16* __restrict__ in, u16* __restrict__ out,
    const float* __restrict__ gamma)
{
    if (gamma[0] == 0.f) return;
    __shared__ u16 tile[32][33];
    const int x0 = blockIdx.x * 32, y0 = blockIdx.y * 32;
    const int tx = threadIdx.x, ty = threadIdx.y;
    for (int pp = 0; pp < 16; ++pp) {
        const int plane = blockIdx.z * 16 + pp;
        const u16* ip = in + (size_t)plane * HW;
        u16* op = out + (size_t)plane * HW;
#pragma unroll
        for (int u = 0; u < 4; ++u)
            tile[ty + u * 8][tx] = ip[(size_t)(y0 + ty + u * 8) * WW + x0 + tx];
        __syncthreads();
#pragma unroll
        for (int u = 0; u < 4; ++u)
            op[(size_t)(x0 + ty + u * 8) * HH + y0 + tx] = tile[tx][ty + u * 8];
        __syncthreads();
    }
}

// ---------------------------------------------------------------------------
// energy_H per (b,w): EHt[b,w,i,j] = sum_c q[b,c,i,w]*k[b,c,j,w]; diag=-1e30
// ---------------------------------------------------------------------------
__global__ __launch_bounds__(256) void energy_h_kernel(
    const float* __restrict__ q, const float* __restrict__ k,
    u16* __restrict__ EHt, const float* __restrict__ gamma)
{
    if (gamma[0] == 0.f) return;
    const int w = blockIdx.x, bz = blockIdx.y, t = threadIdx.x;
    __shared__ float qc[32][128];
    __shared__ float kc[32][128];
    __shared__ u16 es[128][128];
    for (int it = 0; it < 16; ++it) {
        int idx = it * 256 + t;
        int c = idx >> 7, j = idx & 127;
        qc[c][j] = q[((size_t)bz * CQK + c) * HW + j * WW + w];
        kc[c][j] = k[((size_t)bz * CQK + c) * HW + j * WW + w];
    }
    __syncthreads();
    const int i = t & 127, half = t >> 7, j0 = half * 64;
    float qi[32];
#pragma unroll
    for (int c = 0; c < 32; ++c) qi[c] = qc[c][i];
    for (int j = j0; j < j0 + 64; ++j) {
        float acc = 0.f;
#pragma unroll
        for (int c = 0; c < 32; ++c) acc += qi[c] * kc[c][j];
        es[i][j] = f2us(i == j ? -1e30f : acc);
    }
    __syncthreads();
    u16* dst = EHt + ((size_t)bz * WW + w) * HW;
    for (int it = 0; it < 8; ++it) {
        int ii = it * 16 + (t >> 4), jj = (t & 15) * 8;
        *reinterpret_cast<uint4*>(&dst[(size_t)ii * HH + jj]) =
            *reinterpret_cast<const uint4*>(&es[ii][jj]);
    }
}

// ---------------------------------------------------------------------------
// per (b,r): energy_W in LDS, joint softmax over [E_H row | E_W row] (256),
// writes normalized att_H back into EHt, computes O_W with 1/denom folded in.
// ---------------------------------------------------------------------------
__global__ __launch_bounds__(256) void ew_softmax_ow_kernel(
    const float* __restrict__ q, const float* __restrict__ k,
    const u16* __restrict__ v, u16* __restrict__ EHt,
    u16* __restrict__ oW, const float* __restrict__ gamma)
{
    if (gamma[0] == 0.f) return;
    const int r = blockIdx.x, bz = blockIdx.y, t = threadIdx.x;
    __shared__ float qr[32][128];
    __shared__ float kr[32][128];
    __shared__ u16 ewT[128][136];
    __shared__ u16 vstageT[128][40];
    __shared__ float invA[128];
    __shared__ float red[2][2][128];

    for (int it = 0; it < 16; ++it) {
        int idx = it * 256 + t, c = idx >> 7, j = idx & 127;
        qr[c][j] = q[((size_t)bz * CQK + c) * HW + r * WW + j];
        kr[c][j] = k[((size_t)bz * CQK + c) * HW + r * WW + j];
    }
    __syncthreads();
    const int i = t & 127, half = t >> 7, j0 = half * 64;
    {
        float qi[32];
#pragma unroll
        for (int c = 0; c < 32; ++c) qi[c] = qr[c][i];
        for (int j = j0; j < j0 + 64; ++j) {
            float acc = 0.f;
#pragma unroll
            for (int c = 0; c < 32; ++c) acc += qi[c] * kr[c][j];
            ewT[j][i] = f2us(acc);
        }
    }
    __syncthreads();
    float eh[64];
    u16* ehrow = EHt + (((size_t)bz * WW + i) * HH + r) * HH + j0;
#pragma unroll
    for (int uq = 0; uq < 8; ++uq) {
        uint4 pk = *reinterpret_cast<const uint4*>(ehrow + uq * 8);
        unpack8(pk, eh + uq * 8);
    }
    float m = -3e38f;
#pragma unroll
    for (int u = 0; u < 64; ++u) m = fmaxf(m, eh[u]);
    for (int j = j0; j < j0 + 64; ++j) m = fmaxf(m, us2f(ewT[j][i]));
    red[0][half][i] = m;
    __syncthreads();
    m = fmaxf(red[0][0][i], red[0][1][i]);
    float s = 0.f;
#pragma unroll
    for (int u = 0; u < 64; ++u) { float e = __expf(eh[u] - m); eh[u] = e; s += e; }
    for (int j = j0; j < j0 + 64; ++j) {
        float e = __expf(us2f(ewT[j][i]) - m);
        ewT[j][i] = f2us(e);
        s += e;
    }
    red[1][half][i] = s;
    __syncthreads();
    const float inv = 1.f / (red[1][0][i] + red[1][1][i]);
    if (half == 0) invA[i] = inv;
#pragma unroll
    for (int uq = 0; uq < 8; ++uq) {
        alignas(16) u16 tmp[8];
#pragma unroll
        for (int e = 0; e < 8; ++e) tmp[e] = f2us(eh[uq * 8 + e] * inv);
        *reinterpret_cast<uint4*>(ehrow + uq * 8) = *reinterpret_cast<uint4*>(tmp);
    }
    const int cg = half;
    for (int c0 = 0; c0 < C2; c0 += 32) {
        __syncthreads();
        for (int it = 0; it < 16; ++it) {
            int idx = it * 256 + t, cc = idx >> 7, j = idx & 127;
            vstageT[j][cc] = v[((size_t)bz * C2 + c0 + cc) * HW + r * WW + j];
        }
        __syncthreads();
        float acc[16] = {};
        for (int j = 0; j < 128; ++j) {
            float a = us2f(ewT[j][i]);
            uint4 pq0 = *reinterpret_cast<const uint4*>(&vstageT[j][cg * 16]);
            uint4 pq1 = *reinterpret_cast<const uint4*>(&vstageT[j][cg * 16 + 8]);
            float vv[16];
            unpack8(pq0, vv);
            unpack8(pq1, vv + 8);
#pragma unroll
            for (int u = 0; u < 16; ++u) acc[u] += a * vv[u];
        }
        const float scale = invA[i];
#pragma unroll
        for (int u = 0; u < 16; ++u) {
            int c = c0 + cg * 16 + u;
            oW[((size_t)bz * C2 + c) * HW + r * WW + i] = f2us(acc[u] * scale);
        }
    }
}

// ---------------------------------------------------------------------------
// O_H per (b,w): oHT[b,c,w,i] = sum_j vT[b,c,w,j] * attH[b,w,i,j]
// ---------------------------------------------------------------------------
__global__ __launch_bounds__(256) void apply_h_kernel(
    const u16* __restrict__ EHt, const u16* __restrict__ vT,
    u16* __restrict__ oHT, const float* __restrict__ gamma)
{
    if (gamma[0] == 0.f) return;
    const int w = blockIdx.x, bz = blockIdx.y, t = threadIdx.x;
    __shared__ u16 aT[128][136];
    __shared__ u16 vstageT[128][40];
    const u16* src = EHt + ((size_t)bz * WW + w) * HW;
    for (int it = 0; it < 8; ++it) {
        int oct = it * 256 + t;
        int ii = oct >> 4, jj = (oct & 15) * 8;
        U8 uu;
        uu.v = *reinterpret_cast<const uint4*>(src + (size_t)ii * HH + jj);
#pragma unroll
        for (int e = 0; e < 8; ++e) aT[jj + e][ii] = uu.s[e];
    }
    const int i = t & 127, cg = t >> 7;
    for (int c0 = 0; c0 < C2; c0 += 32) {
        __syncthreads();
        for (int it = 0; it < 16; ++it) {
            int idx = it * 256 + t, cc = idx >> 7, j = idx & 127;
            vstageT[j][cc] = vT[((size_t)bz * C2 + c0 + cc) * HW + w * HH + j];
        }
        __syncthreads();
        float acc[16] = {};
        for (int j = 0; j < 128; ++j) {
            float a = us2f(aT[j][i]);
            uint4 pq0 = *reinterpret_cast<const uint4*>(&vstageT[j][cg * 16]);
            uint4 pq1 = *reinterpret_cast<const uint4*>(&vstageT[j][cg * 16 + 8]);
            float vv[16];
            unpack8(pq0, vv);
            unpack8(pq1, vv + 8);
#pragma unroll
            for (int u = 0; u < 16; ++u) acc[u] += a * vv[u];
        }
#pragma unroll
        for (int u = 0; u < 16; ++u) {
            int c = c0 + cg * 16 + u;
            oHT[((size_t)bz * C2 + c) * HW + w * HH + i] = f2us(acc[u]);
        }
    }
}

// ---------------------------------------------------------------------------
// y[b,c,i,w] = gamma*(oHT[b,c,w,i] + oW[b,c,i,w]) + x[b,c,i,w]  (bf16 out)
// ---------------------------------------------------------------------------
__global__ __launch_bounds__(256) void merge_transpose_kernel(
    const u16* __restrict__ oHT, const u16* __restrict__ oW,
    const float* __restrict__ x1, const float* __restrict__ x2,
    const float* __restrict__ gamma, u16* __restrict__ y, int b0)
{
    const float g = gamma[0];
    if (g == 0.f) return;
    __shared__ float tile[32][33];
    const int w0 = blockIdx.x * 32, i0 = blockIdx.y * 32;
    const int tx = threadIdx.x, ty = threadIdx.y;
    for (int pp = 0; pp < 16; ++pp) {
        const int idx = blockIdx.z * 16 + pp;
        const int c = idx & 511, bz = idx >> 9;
        const int bg = b0 + bz;
        const u16* ih = oHT + ((size_t)bz * C2 + c) * HW;
#pragma unroll
        for (int u = 0; u < 4; ++u)
            tile[ty + u * 8][tx] = us2f(ih[(size_t)(w0 + ty + u * 8) * HH + i0 + tx]);
        __syncthreads();
        const float* xs = (c < 256) ? (x1 + ((size_t)bg * 256 + c) * HW)
                                    : (x2 + ((size_t)bg * 256 + (c - 256)) * HW);
        const u16* ow = oW + ((size_t)bz * C2 + c) * HW;
        u16* yy = y + ((size_t)bz * C2 + c) * HW;
#pragma unroll
        for (int u = 0; u < 4; ++u) {
            int i = i0 + ty + u * 8, w = w0 + tx;
            float oh = tile[tx][ty + u * 8];
            float val = g * (oh + us2f(ow[(size_t)i * WW + w])) + xs[(size_t)i * WW + w];
            yy[(size_t)i * WW + w] = f2us(val);
        }
        __syncthreads();
    }
}

// ---------------------------------------------------------------------------
extern "C" void kernel_launch(void* const* d_in, const int* in_sizes, int n_in,
                              void* d_out, int out_size, void* d_ws, size_t ws_size,
                              hipStream_t stream)
{
    const float* x1 = (const float*)d_in[0];
    const float* x2 = (const float*)d_in[1];
    const float* Wq = (const float*)d_in[2];
    const float* bq = (const float*)d_in[3];
    const float* Wk = (const float*)d_in[4];
    const float* bk = (const float*)d_in[5];
    const float* Wv = (const float*)d_in[6];
    const float* bv = (const float*)d_in[7];
    const float* Wm = (const float*)d_in[8];
    const float* bm = (const float*)d_in[9];
    const float* gamma = (const float*)d_in[10];
    float* out = (float*)d_out;

    auto algn = [](size_t v) { return (v + 255) & ~(size_t)255; };
    const size_t wallSz = algn((size_t)1088 * 512 * 2);
    auto need = [&](int nb) -> size_t {
        size_t s = wallSz;
        s += algn((size_t)nb * HW * 512 * 2);      // xT
        s += 2 * algn((size_t)nb * 32 * HW * 4);   // q,k
        s += algn((size_t)nb * C2 * HW * 2);       // v
        s += algn((size_t)nb * C2 * HW * 2);       // vT (alias y)
        s += algn((size_t)nb * WW * HW * 2);       // EHt
        s += algn((size_t)nb * C2 * HW * 2);       // oW
        s += algn((size_t)nb * C2 * HW * 2);       // oHT
        return s;
    };
    const int nb = (ws_size >= need(4)) ? 4 : (ws_size >= need(2)) ? 2 : 1;

    char* base = (char*)d_ws;
    u16* Wall = (u16*)base; base += wallSz;
    const u16* Wqk = Wall;
    const u16* Wvb = Wall + (size_t)64 * 512;
    const u16* Wmb = Wall + (size_t)576 * 512;

    convert_weights<<<(1088 * 128 + 255) / 256, 256, 0, stream>>>(
        Wq, Wk, Wv, Wm, Wall, gamma);

    for (int b0 = 0; b0 < NB_TOT; b0 += nb) {
        char* p = base;
        u16* xT   = (u16*)p;   p += algn((size_t)nb * HW * 512 * 2);
        float* q  = (float*)p; p += algn((size_t)nb * 32 * HW * 4);
        float* kk = (float*)p; p += algn((size_t)nb * 32 * HW * 4);
        u16* v    = (u16*)p;   p += algn((size_t)nb * C2 * HW * 2);
        u16* vT   = (u16*)p;   p += algn((size_t)nb * C2 * HW * 2);
        u16* EHt  = (u16*)p;   p += algn((size_t)nb * WW * HW * 2);
        u16* oW   = (u16*)p;   p += algn((size_t)nb * C2 * HW * 2);
        u16* oHT  = (u16*)p;   p += algn((size_t)nb * C2 * HW * 2);
        u16* y    = vT;  // vT dead after apply_h

        // ---- attention path (all gamma-guarded, early-exit when gamma==0) --
        transpose_x<<<dim3(HW / 32, 1, nb), dim3(32, 8), 0, stream>>>(
            x1, x2, xT, b0, gamma);
        conv_mfma<64, 0><<<dim3(HW / 128, 1, nb), 256, 0, stream>>>(
            Wqk, bq, bk, xT, q, kk, nullptr, b0, gamma);
        conv_mfma<128, 1><<<dim3(HW / 128, 4, nb), 256, 0, stream>>>(
            Wvb, bv, nullptr, xT, nullptr, nullptr, v, b0, gamma);
        transpose_bf16<<<dim3(4, 4, nb * 32), dim3(32, 8), 0, stream>>>(v, vT, gamma);
        energy_h_kernel<<<dim3(WW, nb), 256, 0, stream>>>(q, kk, EHt, gamma);
        ew_softmax_ow_kernel<<<dim3(HH, nb), 256, 0, stream>>>(q, kk, v, EHt, oW, gamma);
        apply_h_kernel<<<dim3(WW, nb), 256, 0, stream>>>(EHt, vT, oHT, gamma);
        merge_transpose_kernel<<<dim3(4, 4, nb * 32), dim3(32, 8), 0, stream>>>(
            oHT, oW, x1, x2, gamma, y, b0);
        // ---- final conv (always; reads x directly when gamma==0, y else) --
        conv_final<<<dim3(HW / 128, 1, nb), 512, 0, stream>>>(
            Wmb, bm, x1, x2, y, out, b0, gamma);
    }
}

// Round 13
// 86.854 us; speedup vs baseline: 4.6710x; 4.6710x over previous
//
#include <hip/hip_runtime.h>
#include <cstdint>

#define HW 16384
#define HH 128
#define WW 128
#define C2 512
#define CQK 32
#define NB_TOT 4

typedef unsigned short u16;
typedef unsigned int u32;

using bf16x8 = __attribute__((ext_vector_type(8))) short;
using f32x4  = __attribute__((ext_vector_type(4))) float;

__device__ __forceinline__ float us2f(u16 u) { return __uint_as_float(((u32)u) << 16); }
__device__ __forceinline__ u16 f2us(float f) {
    u32 u = __float_as_uint(f);
    u = u + 0x7fffu + ((u >> 16) & 1u);
    return (u16)(u >> 16);
}
__device__ __forceinline__ u32 pack2(float a, float b) {
    return (u32)f2us(a) | ((u32)f2us(b) << 16);
}
__device__ __forceinline__ void unpack8(uint4 p, float* f) {
    u32 a[4] = {p.x, p.y, p.z, p.w};
#pragma unroll
    for (int q = 0; q < 4; ++q) {
        f[q * 2 + 0] = __uint_as_float(a[q] << 16);
        f[q * 2 + 1] = __uint_as_float(a[q] & 0xffff0000u);
    }
}
union U8 { uint4 v; u16 s[8]; };

__device__ __forceinline__ void gl_lds16(const void* g, const void* lds) {
    __builtin_amdgcn_global_load_lds(
        (const __attribute__((address_space(1))) unsigned int*)g,
        (__attribute__((address_space(3))) unsigned int*)lds, 16, 0, 0);
}

// ---------------------------------------------------------------------------
// Convert weights fp32 -> bf16. rows [0,64)=q|k, [64,576)=v, [576,1088)=m.
// ---------------------------------------------------------------------------
__global__ __launch_bounds__(256) void convert_weights(
    const float* __restrict__ Wq, const float* __restrict__ Wk,
    const float* __restrict__ Wv, const float* __restrict__ Wm,
    u16* __restrict__ Wall, const float* __restrict__ gamma)
{
    int id = blockIdx.x * 256 + threadIdx.x;  // one float4 each
    if (id >= 1088 * 128) return;
    int row = id >> 7, q4 = id & 127;
    if (row < 576 && gamma[0] == 0.f) return;  // attention-only rows
    const float* src;
    if (row < 32) src = Wq + (size_t)row * 512;
    else if (row < 64) src = Wk + (size_t)(row - 32) * 512;
    else if (row < 576) src = Wv + (size_t)(row - 64) * 512;
    else src = Wm + (size_t)(row - 576) * 512;
    float4 v = *reinterpret_cast<const float4*>(src + q4 * 4);
    alignas(8) u16 h[4] = {f2us(v.x), f2us(v.y), f2us(v.z), f2us(v.w)};
    *reinterpret_cast<uint2*>(Wall + (size_t)row * 512 + q4 * 4) =
        *reinterpret_cast<uint2*>(h);
}

// ---------------------------------------------------------------------------
// FINAL CONV (always runs): out[s,bg,cc,p] = Wm[m]·src + bm.
// src = bf16(x) (gamma==0) or y (gamma!=0), [c][p] layout; transpose in LDS.
// R13: BM=512, BN=64, BK=32, 8 waves, As dbuf + X reg-staged 1 ahead
// (champion pipeline), 69KB LDS + acc[4][4]=64 VGPR -> true 2 blocks/CU
// (R12's spill bug fixed by halving BN so (512,4) register bound fits).
// ---------------------------------------------------------------------------
__global__ __launch_bounds__(512, 4) void conv_final(
    const u16* __restrict__ Wmb, const float* __restrict__ bm,
    const float* __restrict__ x1, const float* __restrict__ x2,
    const u16* __restrict__ y, float* __restrict__ out,
    int b0, const float* __restrict__ gamma)
{
    __shared__ u16 As[2][512 * 32];  // 2x32KB [m][32k], chunk ck at slot ck^(m&3)
    __shared__ u32 Ps[64 * 20];      // 5KB [p][16 dword cols + 4 pad]; dword=(c,c+1)
    const int t = threadIdx.x, lane = t & 63, wid = t >> 6;  // 8 waves
    const int bz = blockIdx.z, bg = b0 + bz;
    const int p0 = blockIdx.x * 64;
    const int l15 = lane & 15, l16 = lane >> 4;
    const bool useY = (gamma[0] != 0.f);
    const int pcol = t & 31, cpair = t >> 5;  // cpair 0..15 (32 ch = 16 pairs)
    const u16* yb = y + (size_t)bz * C2 * HW;

    f32x4 acc[4][4];
#pragma unroll
    for (int i = 0; i < 4; ++i)
#pragma unroll
        for (int j = 0; j < 4; ++j) acc[i][j] = (f32x4)0.f;

    u32 xr[4];  // row ce: xr[0,1] at pcol,pcol+32; row ce+1: xr[2,3]

    auto loadX = [&](int k0) {
        const int ce = k0 + cpair * 2;         // even channel; ce+1 adjacent
        if (useY) {
            const u16* s0 = yb + (size_t)ce * HW + p0;
            const u16* s1 = s0 + HW;
            xr[0] = s0[pcol]; xr[1] = s0[pcol + 32];
            xr[2] = s1[pcol]; xr[3] = s1[pcol + 32];
        } else {
            // ce even -> ce, ce+1 always in the same tensor
            const float* s0 = (ce < 256) ? x1 + ((size_t)bg * 256 + ce) * HW + p0
                                         : x2 + ((size_t)bg * 256 + ce - 256) * HW + p0;
            const float* s1 = s0 + HW;
            xr[0] = __float_as_uint(s0[pcol]); xr[1] = __float_as_uint(s0[pcol + 32]);
            xr[2] = __float_as_uint(s1[pcol]); xr[3] = __float_as_uint(s1[pcol + 32]);
        }
    };
    auto writeX = [&]() {
#pragma unroll
        for (int i = 0; i < 2; ++i) {
            int p = pcol + i * 32;
            u32 d = useY ? (xr[i] | (xr[2 + i] << 16))
                         : pack2(__uint_as_float(xr[i]), __uint_as_float(xr[2 + i]));
            Ps[p * 20 + cpair] = d;
        }
    };
    auto stageW = [&](int k0, int b) {
        // 512 rows x 4 chunks = 2048 slots; 4 per thread; XOR swizzle low2
#pragma unroll
        for (int it = 0; it < 4; ++it) {
            int sflat = it * 512 + t;          // LDS 16B-slot index (linear)
            int m = sflat >> 2, slot = sflat & 3;
            int ck = slot ^ (m & 3);           // logical chunk at this slot
            gl_lds16(Wmb + (size_t)m * 512 + k0 + ck * 8, &As[b][sflat * 8]);
        }
    };

    // prologue: fill W buf0 + X
    stageW(0, 0);
    loadX(0);
    writeX();          // auto-waits X loads via reg deps
    __syncthreads();   // drains W gl_lds (vmcnt0) + lgkm

    for (int k = 0; k < 16; ++k) {
        const int cb = k & 1;
        if (k < 15) {
            stageW((k + 1) * 32, cb ^ 1);  // async into other buffer
            loadX((k + 1) * 32);           // regs in flight under compute
        }
        // ---- compute step k: 16 MFMA per wave ----
        {
            bf16x8 af[4];
#pragma unroll
            for (int mi = 0; mi < 4; ++mi) {
                int row = wid * 64 + mi * 16 + l15;
                int slot = l16 ^ (row & 3);
                af[mi] = *(const bf16x8*)&As[cb][row * 32 + slot * 8];
            }
#pragma unroll
            for (int ni = 0; ni < 4; ++ni) {
                bf16x8 bq = *(const bf16x8*)((const u16*)&Ps[(ni * 16 + l15) * 20 + l16 * 4]);
#pragma unroll
                for (int mi = 0; mi < 4; ++mi)
                    acc[mi][ni] = __builtin_amdgcn_mfma_f32_16x16x32_bf16(
                        af[mi], bq, acc[mi][ni], 0, 0, 0);
            }
        }
        __syncthreads();             // all reads of Ps/As[cb] done; W(k+1) landed
        if (k < 15) {
            writeX();                // stage X(k+1) into Ps
            __syncthreads();         // lgkm drain so next compute sees it
        }
    }
    // ---- epilogue: bias + permuted fp32 store ----
#pragma unroll
    for (int mi = 0; mi < 4; ++mi)
#pragma unroll
        for (int ni = 0; ni < 4; ++ni) {
            const int p = p0 + ni * 16 + l15;
#pragma unroll
            for (int r = 0; r < 4; ++r) {
                const int m = wid * 64 + mi * 16 + l16 * 4 + r;
                out[(((size_t)(m >> 8) * NB_TOT + bg) * 256 + (m & 255)) * HW + p] =
                    acc[mi][ni][r] + bm[m];
            }
        }
}

// ---------------------------------------------------------------------------
// xT[bz][p][c] = bf16(x[bg][c][p])  — ATTENTION PATH ONLY (gamma!=0).
// ---------------------------------------------------------------------------
__global__ __launch_bounds__(256) void transpose_x(
    const float* __restrict__ x1, const float* __restrict__ x2,
    u16* __restrict__ xT, int b0, const float* __restrict__ gamma)
{
    if (gamma[0] == 0.f) return;
    __shared__ u16 tile[32][33];
    const int bz = blockIdx.z, bg = b0 + bz;
    const int p0 = blockIdx.x * 32;
    const int tx = threadIdx.x, ty = threadIdx.y;
    for (int cy = 0; cy < 16; ++cy) {
        const int c0 = cy * 32;
#pragma unroll
        for (int u = 0; u < 4; ++u) {
            int c = c0 + ty + u * 8;
            const float* xs = (c < 256) ? x1 + ((size_t)bg * 256 + c) * HW
                                        : x2 + ((size_t)bg * 256 + (c - 256)) * HW;
            tile[ty + u * 8][tx] = f2us(xs[p0 + tx]);
        }
        __syncthreads();
#pragma unroll
        for (int u = 0; u < 4; ++u) {
            int p = p0 + ty + u * 8;
            xT[((size_t)bz * HW + p) * 512 + c0 + tx] = tile[tx][ty + u * 8];
        }
        __syncthreads();
    }
}

// ---------------------------------------------------------------------------
// MFMA 1x1-conv (attention path): out[m][p] = sum_c W[m][c]*xT[p][c].
// MODE 0: M=64 q|k fp32. MODE 1: M=512 -> bf16 v. Both gamma-guarded.
// ---------------------------------------------------------------------------
template <int BM, int MODE>
__global__ __launch_bounds__(256) void conv_mfma(
    const u16* __restrict__ Wb, const float* __restrict__ bias0,
    const float* __restrict__ bias1, const u16* __restrict__ xT,
    float* __restrict__ oQ, float* __restrict__ oK,
    u16* __restrict__ oV, int b0, const float* __restrict__ gamma)
{
    if (gamma[0] == 0.f) return;
    constexpr int FM = BM / 32;
    __shared__ u16 As[BM * 64];
    __shared__ u16 Ps[128 * 64];
    const int t = threadIdx.x, lane = t & 63, wid = t >> 6;
    const int wr = wid >> 1, wc = wid & 1;
    const int bz = blockIdx.z;
    const int p0 = blockIdx.x * 128, m0 = blockIdx.y * BM;
    const u16* xTb = xT + (size_t)bz * HW * 512;
    const int l15 = lane & 15, l16 = lane >> 4;

    f32x4 acc[FM][4];
#pragma unroll
    for (int i = 0; i < FM; ++i)
#pragma unroll
        for (int j = 0; j < 4; ++j) acc[i][j] = (f32x4)0.f;

    for (int c0 = 0; c0 < 512; c0 += 64) {
#pragma unroll
        for (int it = 0; it < BM / 32; ++it) {
            int flat = it * 256 + t;
            int row = flat >> 3, part = flat & 7;
            gl_lds16(Wb + (size_t)(m0 + row) * 512 + c0 + part * 8,
                     As + (it * 256 + wid * 64) * 8);
        }
#pragma unroll
        for (int it = 0; it < 4; ++it) {
            int flat = it * 256 + t;
            int row = flat >> 3, part = flat & 7;
            gl_lds16(xTb + (size_t)(p0 + row) * 512 + c0 + part * 8,
                     Ps + (it * 256 + wid * 64) * 8);
        }
        __syncthreads();
#pragma unroll
        for (int kk = 0; kk < 2; ++kk) {
            bf16x8 af[FM], bfr[4];
#pragma unroll
            for (int mi = 0; mi < FM; ++mi)
                af[mi] = *(const bf16x8*)&As[(wr * (BM / 2) + mi * 16 + l15) * 64 + kk * 32 + l16 * 8];
#pragma unroll
            for (int ni = 0; ni < 4; ++ni)
                bfr[ni] = *(const bf16x8*)&Ps[(wc * 64 + ni * 16 + l15) * 64 + kk * 32 + l16 * 8];
#pragma unroll
            for (int mi = 0; mi < FM; ++mi)
#pragma unroll
                for (int ni = 0; ni < 4; ++ni)
                    acc[mi][ni] = __builtin_amdgcn_mfma_f32_16x16x32_bf16(
                        af[mi], bfr[ni], acc[mi][ni], 0, 0, 0);
        }
        __syncthreads();
    }
#pragma unroll
    for (int mi = 0; mi < FM; ++mi)
#pragma unroll
        for (int ni = 0; ni < 4; ++ni) {
            const int p = p0 + wc * 64 + ni * 16 + l15;
#pragma unroll
            for (int r = 0; r < 4; ++r) {
                const int m = m0 + wr * (BM / 2) + mi * 16 + l16 * 4 + r;
                float val = acc[mi][ni][r];
                if (MODE == 0) {
                    if (m < 32) {
                        val += bias0[m];
                        oQ[((size_t)bz * 32 + m) * HW + p] = val;
                    } else {
                        val += bias1[m - 32];
                        oK[((size_t)bz * 32 + (m - 32)) * HW + p] = val;
                    }
                } else {
                    val += bias0[m];
                    oV[((size_t)bz * 512 + m) * HW + p] = f2us(val);
                }
            }
        }
}

// ---------------------------------------------------------------------------
// 128x128 plane transpose, bf16 (v -> vT). Guarded; plane-looped grid.
// ---------------------------------------------------------------------------
__global__ __launch_bounds__(256) void transpose_bf16(
    const u16* __restrict__ in, u16* __restrict__ out,
    const float* __restrict__ gamma)
{
    if (gamma[0] == 0.f) return;
    __shared__ u16 tile[32][33];
    const int x0 = blockIdx.x * 32, y0 = blockIdx.y * 32;
    const int tx = threadIdx.x, ty = threadIdx.y;
    for (int pp = 0; pp < 16; ++pp) {
        const int plane = blockIdx.z * 16 + pp;
        const u16* ip = in + (size_t)plane * HW;
        u16* op = out + (size_t)plane * HW;
#pragma unroll
        for (int u = 0; u < 4; ++u)
            tile[ty + u * 8][tx] = ip[(size_t)(y0 + ty + u * 8) * WW + x0 + tx];
        __syncthreads();
#pragma unroll
        for (int u = 0; u < 4; ++u)
            op[(size_t)(x0 + ty + u * 8) * HH + y0 + tx] = tile[tx][ty + u * 8];
        __syncthreads();
    }
}

// ---------------------------------------------------------------------------
// energy_H per (b,w): EHt[b,w,i,j] = sum_c q[b,c,i,w]*k[b,c,j,w]; diag=-1e30
// ---------------------------------------------------------------------------
__global__ __launch_bounds__(256) void energy_h_kernel(
    const float* __restrict__ q, const float* __restrict__ k,
    u16* __restrict__ EHt, const float* __restrict__ gamma)
{
    if (gamma[0] == 0.f) return;
    const int w = blockIdx.x, bz = blockIdx.y, t = threadIdx.x;
    __shared__ float qc[32][128];
    __shared__ float kc[32][128];
    __shared__ u16 es[128][128];
    for (int it = 0; it < 16; ++it) {
        int idx = it * 256 + t;
        int c = idx >> 7, j = idx & 127;
        qc[c][j] = q[((size_t)bz * CQK + c) * HW + j * WW + w];
        kc[c][j] = k[((size_t)bz * CQK + c) * HW + j * WW + w];
    }
    __syncthreads();
    const int i = t & 127, half = t >> 7, j0 = half * 64;
    float qi[32];
#pragma unroll
    for (int c = 0; c < 32; ++c) qi[c] = qc[c][i];
    for (int j = j0; j < j0 + 64; ++j) {
        float acc = 0.f;
#pragma unroll
        for (int c = 0; c < 32; ++c) acc += qi[c] * kc[c][j];
        es[i][j] = f2us(i == j ? -1e30f : acc);
    }
    __syncthreads();
    u16* dst = EHt + ((size_t)bz * WW + w) * HW;
    for (int it = 0; it < 8; ++it) {
        int ii = it * 16 + (t >> 4), jj = (t & 15) * 8;
        *reinterpret_cast<uint4*>(&dst[(size_t)ii * HH + jj]) =
            *reinterpret_cast<const uint4*>(&es[ii][jj]);
    }
}

// ---------------------------------------------------------------------------
// per (b,r): energy_W in LDS, joint softmax over [E_H row | E_W row] (256),
// writes normalized att_H back into EHt, computes O_W with 1/denom folded in.
// ---------------------------------------------------------------------------
__global__ __launch_bounds__(256) void ew_softmax_ow_kernel(
    const float* __restrict__ q, const float* __restrict__ k,
    const u16* __restrict__ v, u16* __restrict__ EHt,
    u16* __restrict__ oW, const float* __restrict__ gamma)
{
    if (gamma[0] == 0.f) return;
    const int r = blockIdx.x, bz = blockIdx.y, t = threadIdx.x;
    __shared__ float qr[32][128];
    __shared__ float kr[32][128];
    __shared__ u16 ewT[128][136];
    __shared__ u16 vstageT[128][40];
    __shared__ float invA[128];
    __shared__ float red[2][2][128];

    for (int it = 0; it < 16; ++it) {
        int idx = it * 256 + t, c = idx >> 7, j = idx & 127;
        qr[c][j] = q[((size_t)bz * CQK + c) * HW + r * WW + j];
        kr[c][j] = k[((size_t)bz * CQK + c) * HW + r * WW + j];
    }
    __syncthreads();
    const int i = t & 127, half = t >> 7, j0 = half * 64;
    {
        float qi[32];
#pragma unroll
        for (int c = 0; c < 32; ++c) qi[c] = qr[c][i];
        for (int j = j0; j < j0 + 64; ++j) {
            float acc = 0.f;
#pragma unroll
            for (int c = 0; c < 32; ++c) acc += qi[c] * kr[c][j];
            ewT[j][i] = f2us(acc);
        }
    }
    __syncthreads();
    float eh[64];
    u16* ehrow = EHt + (((size_t)bz * WW + i) * HH + r) * HH + j0;
#pragma unroll
    for (int uq = 0; uq < 8; ++uq) {
        uint4 pk = *reinterpret_cast<const uint4*>(ehrow + uq * 8);
        unpack8(pk, eh + uq * 8);
    }
    float m = -3e38f;
#pragma unroll
    for (int u = 0; u < 64; ++u) m = fmaxf(m, eh[u]);
    for (int j = j0; j < j0 + 64; ++j) m = fmaxf(m, us2f(ewT[j][i]));
    red[0][half][i] = m;
    __syncthreads();
    m = fmaxf(red[0][0][i], red[0][1][i]);
    float s = 0.f;
#pragma unroll
    for (int u = 0; u < 64; ++u) { float e = __expf(eh[u] - m); eh[u] = e; s += e; }
    for (int j = j0; j < j0 + 64; ++j) {
        float e = __expf(us2f(ewT[j][i]) - m);
        ewT[j][i] = f2us(e);
        s += e;
    }
    red[1][half][i] = s;
    __syncthreads();
    const float inv = 1.f / (red[1][0][i] + red[1][1][i]);
    if (half == 0) invA[i] = inv;
#pragma unroll
    for (int uq = 0; uq < 8; ++uq) {
        alignas(16) u16 tmp[8];
#pragma unroll
        for (int e = 0; e < 8; ++e) tmp[e] = f2us(eh[uq * 8 + e] * inv);
        *reinterpret_cast<uint4*>(ehrow + uq * 8) = *reinterpret_cast<uint4*>(tmp);
    }
    const int cg = half;
    for (int c0 = 0; c0 < C2; c0 += 32) {
        __syncthreads();
        for (int it = 0; it < 16; ++it) {
            int idx = it * 256 + t, cc = idx >> 7, j = idx & 127;
            vstageT[j][cc] = v[((size_t)bz * C2 + c0 + cc) * HW + r * WW + j];
        }
        __syncthreads();
        float acc[16] = {};
        for (int j = 0; j < 128; ++j) {
            float a = us2f(ewT[j][i]);
            uint4 pq0 = *reinterpret_cast<const uint4*>(&vstageT[j][cg * 16]);
            uint4 pq1 = *reinterpret_cast<const uint4*>(&vstageT[j][cg * 16 + 8]);
            float vv[16];
            unpack8(pq0, vv);
            unpack8(pq1, vv + 8);
#pragma unroll
            for (int u = 0; u < 16; ++u) acc[u] += a * vv[u];
        }
        const float scale = invA[i];
#pragma unroll
        for (int u = 0; u < 16; ++u) {
            int c = c0 + cg * 16 + u;
            oW[((size_t)bz * C2 + c) * HW + r * WW + i] = f2us(acc[u] * scale);
        }
    }
}

// ---------------------------------------------------------------------------
// O_H per (b,w): oHT[b,c,w,i] = sum_j vT[b,c,w,j] * attH[b,w,i,j]
// ---------------------------------------------------------------------------
__global__ __launch_bounds__(256) void apply_h_kernel(
    const u16* __restrict__ EHt, const u16* __restrict__ vT,
    u16* __restrict__ oHT, const float* __restrict__ gamma)
{
    if (gamma[0] == 0.f) return;
    const int w = blockIdx.x, bz = blockIdx.y, t = threadIdx.x;
    __shared__ u16 aT[128][136];
    __shared__ u16 vstageT[128][40];
    const u16* src = EHt + ((size_t)bz * WW + w) * HW;
    for (int it = 0; it < 8; ++it) {
        int oct = it * 256 + t;
        int ii = oct >> 4, jj = (oct & 15) * 8;
        U8 uu;
        uu.v = *reinterpret_cast<const uint4*>(src + (size_t)ii * HH + jj);
#pragma unroll
        for (int e = 0; e < 8; ++e) aT[jj + e][ii] = uu.s[e];
    }
    const int i = t & 127, cg = t >> 7;
    for (int c0 = 0; c0 < C2; c0 += 32) {
        __syncthreads();
        for (int it = 0; it < 16; ++it) {
            int idx = it * 256 + t, cc = idx >> 7, j = idx & 127;
            vstageT[j][cc] = vT[((size_t)bz * C2 + c0 + cc) * HW + w * HH + j];
        }
        __syncthreads();
        float acc[16] = {};
        for (int j = 0; j < 128; ++j) {
            float a = us2f(aT[j][i]);
            uint4 pq0 = *reinterpret_cast<const uint4*>(&vstageT[j][cg * 16]);
            uint4 pq1 = *reinterpret_cast<const uint4*>(&vstageT[j][cg * 16 + 8]);
            float vv[16];
            unpack8(pq0, vv);
            unpack8(pq1, vv + 8);
#pragma unroll
            for (int u = 0; u < 16; ++u) acc[u] += a * vv[u];
        }
#pragma unroll
        for (int u = 0; u < 16; ++u) {
            int c = c0 + cg * 16 + u;
            oHT[((size_t)bz * C2 + c) * HW + w * HH + i] = f2us(acc[u]);
        }
    }
}

// ---------------------------------------------------------------------------
// y[b,c,i,w] = gamma*(oHT[b,c,w,i] + oW[b,c,i,w]) + x[b,c,i,w]  (bf16 out)
// ---------------------------------------------------------------------------
__global__ __launch_bounds__(256) void merge_transpose_kernel(
    const u16* __restrict__ oHT, const u16* __restrict__ oW,
    const float* __restrict__ x1, const float* __restrict__ x2,
    const float* __restrict__ gamma, u16* __restrict__ y, int b0)
{
    const float g = gamma[0];
    if (g == 0.f) return;
    __shared__ float tile[32][33];
    const int w0 = blockIdx.x * 32, i0 = blockIdx.y * 32;
    const int tx = threadIdx.x, ty = threadIdx.y;
    for (int pp = 0; pp < 16; ++pp) {
        const int idx = blockIdx.z * 16 + pp;
        const int c = idx & 511, bz = idx >> 9;
        const int bg = b0 + bz;
        const u16* ih = oHT + ((size_t)bz * C2 + c) * HW;
#pragma unroll
        for (int u = 0; u < 4; ++u)
            tile[ty + u * 8][tx] = us2f(ih[(size_t)(w0 + ty + u * 8) * HH + i0 + tx]);
        __syncthreads();
        const float* xs = (c < 256) ? (x1 + ((size_t)bg * 256 + c) * HW)
                                    : (x2 + ((size_t)bg * 256 + (c - 256)) * HW);
        const u16* ow = oW + ((size_t)bz * C2 + c) * HW;
        u16* yy = y + ((size_t)bz * C2 + c) * HW;
#pragma unroll
        for (int u = 0; u < 4; ++u) {
            int i = i0 + ty + u * 8, w = w0 + tx;
            float oh = tile[tx][ty + u * 8];
            float val = g * (oh + us2f(ow[(size_t)i * WW + w])) + xs[(size_t)i * WW + w];
            yy[(size_t)i * WW + w] = f2us(val);
        }
        __syncthreads();
    }
}

// ---------------------------------------------------------------------------
extern "C" void kernel_launch(void* const* d_in, const int* in_sizes, int n_in,
                              void* d_out, int out_size, void* d_ws, size_t ws_size,
                              hipStream_t stream)
{
    const float* x1 = (const float*)d_in[0];
    const float* x2 = (const float*)d_in[1];
    const float* Wq = (const float*)d_in[2];
    const float* bq = (const float*)d_in[3];
    const float* Wk = (const float*)d_in[4];
    const float* bk = (const float*)d_in[5];
    const float* Wv = (const float*)d_in[6];
    const float* bv = (const float*)d_in[7];
    const float* Wm = (const float*)d_in[8];
    const float* bm = (const float*)d_in[9];
    const float* gamma = (const float*)d_in[10];
    float* out = (float*)d_out;

    auto algn = [](size_t v) { return (v + 255) & ~(size_t)255; };
    const size_t wallSz = algn((size_t)1088 * 512 * 2);
    auto need = [&](int nb) -> size_t {
        size_t s = wallSz;
        s += algn((size_t)nb * HW * 512 * 2);      // xT
        s += 2 * algn((size_t)nb * 32 * HW * 4);   // q,k
        s += algn((size_t)nb * C2 * HW * 2);       // v
        s += algn((size_t)nb * C2 * HW * 2);       // vT (alias y)
        s += algn((size_t)nb * WW * HW * 2);       // EHt
        s += algn((size_t)nb * C2 * HW * 2);       // oW
        s += algn((size_t)nb * C2 * HW * 2);       // oHT
        return s;
    };
    const int nb = (ws_size >= need(4)) ? 4 : (ws_size >= need(2)) ? 2 : 1;

    char* base = (char*)d_ws;
    u16* Wall = (u16*)base; base += wallSz;
    const u16* Wqk = Wall;
    const u16* Wvb = Wall + (size_t)64 * 512;
    const u16* Wmb = Wall + (size_t)576 * 512;

    convert_weights<<<(1088 * 128 + 255) / 256, 256, 0, stream>>>(
        Wq, Wk, Wv, Wm, Wall, gamma);

    for (int b0 = 0; b0 < NB_TOT; b0 += nb) {
        char* p = base;
        u16* xT   = (u16*)p;   p += algn((size_t)nb * HW * 512 * 2);
        float* q  = (float*)p; p += algn((size_t)nb * 32 * HW * 4);
        float* kk = (float*)p; p += algn((size_t)nb * 32 * HW * 4);
        u16* v    = (u16*)p;   p += algn((size_t)nb * C2 * HW * 2);
        u16* vT   = (u16*)p;   p += algn((size_t)nb * C2 * HW * 2);
        u16* EHt  = (u16*)p;   p += algn((size_t)nb * WW * HW * 2);
        u16* oW   = (u16*)p;   p += algn((size_t)nb * C2 * HW * 2);
        u16* oHT  = (u16*)p;   p += algn((size_t)nb * C2 * HW * 2);
        u16* y    = vT;  // vT dead after apply_h

        // ---- attention path (all gamma-guarded, early-exit when gamma==0) --
        transpose_x<<<dim3(HW / 32, 1, nb), dim3(32, 8), 0, stream>>>(
            x1, x2, xT, b0, gamma);
        conv_mfma<64, 0><<<dim3(HW / 128, 1, nb), 256, 0, stream>>>(
            Wqk, bq, bk, xT, q, kk, nullptr, b0, gamma);
        conv_mfma<128, 1><<<dim3(HW / 128, 4, nb), 256, 0, stream>>>(
            Wvb, bv, nullptr, xT, nullptr, nullptr, v, b0, gamma);
        transpose_bf16<<<dim3(4, 4, nb * 32), dim3(32, 8), 0, stream>>>(v, vT, gamma);
        energy_h_kernel<<<dim3(WW, nb), 256, 0, stream>>>(q, kk, EHt, gamma);
        ew_softmax_ow_kernel<<<dim3(HH, nb), 256, 0, stream>>>(q, kk, v, EHt, oW, gamma);
        apply_h_kernel<<<dim3(WW, nb), 256, 0, stream>>>(EHt, vT, oHT, gamma);
        merge_transpose_kernel<<<dim3(4, 4, nb * 32), dim3(32, 8), 0, stream>>>(
            oHT, oW, x1, x2, gamma, y, b0);
        // ---- final conv (always; reads x directly when gamma==0, y else) --
        conv_final<<<dim3(HW / 64, 1, nb), 512, 0, stream>>>(
            Wmb, bm, x1, x2, y, out, b0, gamma);
    }
}